// Round 6
// baseline (945.865 us; speedup 1.0000x reference)
//
#include <hip/hip_runtime.h>
#include <cmath>

constexpr int T_TOK = 8192;   // B*S
constexpr int DM    = 1024;   // d
constexpr int FF    = 4096;   // f
constexpr int NE    = 8;      // experts
constexpr int KTOP  = 2;
constexpr int CAP   = 2560;   // ceil(1.25 * T*K / E)
constexpr int NCHUNK = (T_TOK * KTOP) / 256;   // 64 chunks for the FCFS scan

typedef _Float16 f16x8  __attribute__((ext_vector_type(8)));
typedef float    f32x16 __attribute__((ext_vector_type(16)));

__device__ __forceinline__ void glds16(const void* g, void* l) {
  __builtin_amdgcn_global_load_lds(
      (const __attribute__((address_space(1))) unsigned int*)g,
      (__attribute__((address_space(3))) unsigned int*)l, 16, 0, 0);
}

// sigmoid-form tanh-GELU (algebraically identical to the tanh form, fewer VALU):
// gelu(v) = v / (1 + exp(v*(-1.5957691 - 0.0713548*v^2)))
__device__ __forceinline__ float fast_gelu(float v) {
  float t = __builtin_fmaf(v * v, -0.0713548162f, -1.5957691216f);
  float e = __expf(v * t);
  return v / (1.0f + e);
}

// ---------------- router: fp64 logits/softmax/top-2, one wave per token ----------------
__global__ __launch_bounds__(256) void router_kernel(
    const float* __restrict__ x, const float* __restrict__ Wr,
    const float* __restrict__ br, int* __restrict__ topk_e, float* __restrict__ topk_w)
{
  int wave = threadIdx.x >> 6, lane = threadIdx.x & 63;
  int t = blockIdx.x * 4 + wave;
  const float4* xr4 = (const float4*)(x + (size_t)t * DM);
  double acc[NE];
#pragma unroll
  for (int e = 0; e < NE; ++e) acc[e] = 0.0;
#pragma unroll
  for (int it = 0; it < DM / 4 / 64; ++it) {
    int j4 = it * 64 + lane;
    float4 xv = xr4[j4];
    const float* wr = Wr + (size_t)j4 * 4 * NE;
    float xs[4] = {xv.x, xv.y, xv.z, xv.w};
#pragma unroll
    for (int s = 0; s < 4; ++s) {
      double xd = (double)xs[s];
#pragma unroll
      for (int e = 0; e < NE; ++e) acc[e] += xd * (double)wr[s * NE + e];
    }
  }
#pragma unroll
  for (int off = 32; off >= 1; off >>= 1) {
#pragma unroll
    for (int e = 0; e < NE; ++e) acc[e] += __shfl_down(acc[e], off, 64);
  }
  if (lane == 0) {
    double mx = -1e300;
#pragma unroll
    for (int e = 0; e < NE; ++e) { acc[e] += (double)br[e]; if (acc[e] > mx) mx = acc[e]; }
    double p[NE]; double s = 0.0;
#pragma unroll
    for (int e = 0; e < NE; ++e) { p[e] = exp(acc[e] - mx); s += p[e]; }
#pragma unroll
    for (int e = 0; e < NE; ++e) p[e] /= s;
    int e1 = 0;
    for (int e = 1; e < NE; ++e) if (p[e] > p[e1]) e1 = e;           // ties -> lowest idx
    int e2 = (e1 == 0) ? 1 : 0;
    for (int e = 0; e < NE; ++e) { if (e == e1) continue; if (p[e] > p[e2]) e2 = e; }
    double wsum = p[e1] + p[e2]; if (wsum < 1e-9) wsum = 1e-9;
    topk_e[t*2+0] = e1; topk_e[t*2+1] = e2;
    topk_w[t*2+0] = (float)(p[e1] / wsum);
    topk_w[t*2+1] = (float)(p[e2] / wsum);
  }
}

// ---------------- FCFS capacity scan, parallel 3-phase ----------------
__global__ __launch_bounds__(256) void hist_kernel(
    const int* __restrict__ topk_e, int* __restrict__ hist)   // hist[NCHUNK][NE]
{
  __shared__ int wcnt[4][NE];
  int tid = threadIdx.x, lane = tid & 63, wave = tid >> 6;
  int e = topk_e[blockIdx.x * 256 + tid];
#pragma unroll
  for (int ee = 0; ee < NE; ++ee) {
    unsigned long long m = __ballot(e == ee);
    if (lane == 0) wcnt[wave][ee] = __popcll(m);
  }
  __syncthreads();
  if (tid < NE)
    hist[blockIdx.x * NE + tid] = wcnt[0][tid] + wcnt[1][tid] + wcnt[2][tid] + wcnt[3][tid];
}

__global__ __launch_bounds__(64) void prefix_kernel(
    const int* __restrict__ hist, int* __restrict__ base, int* __restrict__ counts)
{
  int e = threadIdx.x;
  if (e >= NE) return;
  int h[NCHUNK];
#pragma unroll
  for (int c = 0; c < NCHUNK; ++c) h[c] = hist[c * NE + e];
  int b = 0;
#pragma unroll
  for (int c = 0; c < NCHUNK; ++c) { base[c * NE + e] = b; b += h[c]; }
  counts[e] = b < CAP ? b : CAP;
}

__global__ __launch_bounds__(256) void assign_kernel(
    const int* __restrict__ topk_e, const int* __restrict__ base,
    int* __restrict__ assign_slot, int* __restrict__ slot_token)
{
  __shared__ int wcnt[4][NE];
  __shared__ int woff[4][NE];
  int tid = threadIdx.x, lane = tid & 63, wave = tid >> 6;
  int gi = blockIdx.x * 256 + tid;
  int e = topk_e[gi];
  int rank = 0;
  unsigned long long lt = (1ull << lane) - 1ull;
#pragma unroll
  for (int ee = 0; ee < NE; ++ee) {
    unsigned long long m = __ballot(e == ee);
    if (e == ee) rank = __popcll(m & lt);
    if (lane == 0) wcnt[wave][ee] = __popcll(m);
  }
  __syncthreads();
  if (tid < NE) {
    int b = base[blockIdx.x * NE + tid];
#pragma unroll
    for (int w = 0; w < 4; ++w) { woff[w][tid] = b; b += wcnt[w][tid]; }
  }
  __syncthreads();
  int pos = woff[wave][e] + rank;
  bool keep = pos < CAP;
  assign_slot[gi] = keep ? (e * CAP + pos) : -1;
  if (keep) slot_token[e * CAP + pos] = gi >> 1;   // K=2
}

// ---------------- fp32 [E][R][C] -> fp16 [E][C][R], 64x64 tiles, 16B I/O both sides ----------------
__global__ __launch_bounds__(256) void transpose_f16(
    const float* __restrict__ in, _Float16* __restrict__ out, int R, int C)
{
  __shared__ float tile[64][65];
  size_t eoff = (size_t)blockIdx.z * R * C;
  const float* src = in + eoff;
  _Float16* dst = out + eoff;
  int r0 = blockIdx.y * 64, c0 = blockIdx.x * 64;
  int t = threadIdx.x;
  int rr = t >> 4, cc = (t & 15) * 4;          // 16 in-rows per pass, float4 each
#pragma unroll
  for (int i = 0; i < 4; ++i) {
    float4 v = *(const float4*)(src + (size_t)(r0 + rr + i*16) * C + (c0 + cc));
    tile[rr + i*16][cc + 0] = v.x; tile[rr + i*16][cc + 1] = v.y;
    tile[rr + i*16][cc + 2] = v.z; tile[rr + i*16][cc + 3] = v.w;
  }
  __syncthreads();
  int oc = t >> 3, orr = (t & 7) * 8;          // 32 out-rows per pass, 8 fp16 each
#pragma unroll
  for (int i = 0; i < 2; ++i) {
    int c = oc + i * 32;
    _Float16 tmp[8];
#pragma unroll
    for (int j = 0; j < 8; ++j) tmp[j] = (_Float16)tile[orr + j][c];
    *(uint4*)(dst + (size_t)(c0 + c) * R + (r0 + orr)) = *(uint4*)tmp;
  }
}

// ---------------- gather kept tokens into [E][CAP][d] fp16 ----------------
__global__ __launch_bounds__(256) void gather_kernel(
    const float* __restrict__ x, const int* __restrict__ slot_token,
    const int* __restrict__ counts, _Float16* __restrict__ xbuf)
{
  int p = blockIdx.x, e = blockIdx.y;
  if (p >= counts[e]) return;
  int tkn = slot_token[e * CAP + p];
  float4 v = ((const float4*)(x + (size_t)tkn * DM))[threadIdx.x];
  _Float16 tmp[4] = {(_Float16)v.x, (_Float16)v.y, (_Float16)v.z, (_Float16)v.w};
  uint2 bits; __builtin_memcpy(&bits, tmp, 8);
  ((uint2*)(xbuf + ((size_t)e * CAP + p) * DM))[threadIdx.x] = bits;
}

// ---------------- 256x256 fp16 MFMA GEMM, BK=32, fine-phase counted-vmcnt pipeline ----------------
// T3+T4 faithful port. 512 thr = 8 waves (2M x 4N), per-wave out 128x64 (4x2 32x32 frags).
// LDS: 4-slot ring x (A 256x32 + B 256x32) f16 = 128 KB, 1 block/CU.
// Per K-tile t, TWO fine phases (8 MFMA each, m196: fine interleave is the lever):
//   ph0: ds_read A(mi01)+B frags (8 x b128) | stage A(t+3) | BAR | prio1 8 MFMA prio0 | BAR
//   ph1: ds_read A(mi23)        (4 x b128) | stage B(t+3) | vmcnt(8) | BAR | prio1 8 MFMA prio0 | BAR
// vmcnt(8) drains exactly tile t+1's 4 loads (12 outstanding -> 8); never 0 until the
// tail (8->4->0). Loads span 3 tiles (~6 phases) of latency budget.
// Safety: WAR - stage of slot s=(t+3)&3=(t-1)&3 issues after the barrier that follows
// tile t-1's last reads (reads complete before their MFMAs' lgkm wait, which precedes
// that barrier). RAW - vmcnt placed BEFORE the barrier, so every wave confirms its
// own loads landed before any wave reads the new tile.
// Swizzle: LDS[chunk] = G[chunk ^ ((row>>1)&3)], inverted on read; covers all 8
// bank-quads per 8 rows (r5-validated zero-conflict family). glds16 dest is linear
// (base + tid*16), source pre-swizzled per-lane (guide m173 pattern).
// T1: bijective XCD remap, bx innermost. No K-split: GEMM2 = 256 eff blocks = 1.0
// exact round at 1 blk/CU; GEMM1 = 1024 = 4.0 rounds.
template <bool GELU, bool OUTF16>
__global__ __launch_bounds__(512, 2) void gemm8p(
    const _Float16* __restrict__ A, const _Float16* __restrict__ Bt,
    const float* __restrict__ bias, void* __restrict__ Cout,
    const int* __restrict__ counts, int K, int N)
{
  constexpr int BM = 256, BN = 256, BK = 32;
  __shared__ _Float16 As[4][BM * BK];   // 4 x 16KB
  __shared__ _Float16 Bs[4][BN * BK];

  // ---- XCD-aware bijective remap (grid products here are multiples of 8) ----
  int nx = gridDim.x, ny = gridDim.y;
  int w = blockIdx.x + nx * (blockIdx.y + ny * blockIdx.z);
  int nwg = nx * ny * (int)gridDim.z;
  int q8 = nwg >> 3, r8 = nwg & 7;
  int xcd = w & 7, idx = w >> 3;
  int L = (xcd < r8 ? xcd * (q8 + 1) : r8 * (q8 + 1) + (xcd - r8) * q8) + idx;
  int bx = L % nx; int t1 = L / nx; int by = t1 % ny; int e = t1 / ny;

  int Me = counts[e];
  int m0 = by * BM;
  if (m0 >= Me) return;               // capacity padding: skip empty tiles (block-uniform)

  int tid = threadIdx.x, lane = tid & 63, wave = tid >> 6;
  int wm = wave >> 2, wn = wave & 3;           // 2 x 4 waves; wave out 128x64
  const _Float16* Ae = A + ((size_t)e * CAP + m0) * K;
  const _Float16* Be = Bt + ((size_t)e * N + (size_t)bx * BN) * K;
  int n31 = lane & 31, khalf = lane >> 5;
  int srow = tid >> 2, schunk = tid & 3;       // staging: 128 rows x 4 16B-chunks per pass
  int scsw = schunk ^ ((tid >> 3) & 3);        // pre-swizzled source chunk
  int sw = (n31 >> 1) & 3;                     // read-side swizzle
  f32x16 acc[4][2] = {};
  int nt = K / BK;

  auto stageA = [&](int t) {
    int slot = t & 3; int k0 = t * BK;
#pragma unroll
    for (int i = 0; i < 2; ++i) {
      int row = i * 128 + srow;
      glds16(Ae + (size_t)row * K + (k0 + scsw * 8),
             (char*)&As[slot][0] + row * 64 + schunk * 16);
    }
  };
  auto stageB = [&](int t) {
    int slot = t & 3; int k0 = t * BK;
#pragma unroll
    for (int i = 0; i < 2; ++i) {
      int row = i * 128 + srow;
      glds16(Be + (size_t)row * K + (k0 + scsw * 8),
             (char*)&Bs[slot][0] + row * 64 + schunk * 16);
    }
  };

#define FENCE asm volatile("" ::: "memory")
#define BAR   do { FENCE; __builtin_amdgcn_s_barrier(); FENCE; } while (0)

  // prologue: 3 tiles in flight, drain tile 0 only (vmcnt 12 -> 8)
  stageA(0); stageB(0);
  stageA(1); stageB(1);
  stageA(2); stageB(2);
  asm volatile("s_waitcnt vmcnt(8)" ::: "memory");
  BAR;

  for (int t = 0; t < nt; ++t) {
    const _Float16* Aslot = &As[t & 3][0];
    const _Float16* Bslot = &Bs[t & 3][0];
    f16x8 av[2][2], bv[2][2];   // av[mi-in-pair][kk], bv[ni][kk]
    // ---- phase 0: frags for mi01 quadrant-pair + all B ----
#pragma unroll
    for (int kk = 0; kk < 2; ++kk) {
      int coff = (((kk * 2 + khalf) ^ sw) << 3);
#pragma unroll
      for (int mi = 0; mi < 2; ++mi)
        av[mi][kk] = *(const f16x8*)(Aslot + (size_t)(wm * 128 + mi * 32 + n31) * BK + coff);
#pragma unroll
      for (int ni = 0; ni < 2; ++ni)
        bv[ni][kk] = *(const f16x8*)(Bslot + (size_t)(wn * 64 + ni * 32 + n31) * BK + coff);
    }
    if (t + 3 < nt) stageA(t + 3);
    BAR;
    __builtin_amdgcn_s_setprio(1);
#pragma unroll
    for (int kk = 0; kk < 2; ++kk)
#pragma unroll
      for (int mi = 0; mi < 2; ++mi)
#pragma unroll
        for (int ni = 0; ni < 2; ++ni)
          acc[mi][ni] = __builtin_amdgcn_mfma_f32_32x32x16_f16(av[mi][kk], bv[ni][kk], acc[mi][ni], 0, 0, 0);
    __builtin_amdgcn_s_setprio(0);
    BAR;
    // ---- phase 1: frags for mi23 (B reused in regs) ----
#pragma unroll
    for (int kk = 0; kk < 2; ++kk) {
      int coff = (((kk * 2 + khalf) ^ sw) << 3);
#pragma unroll
      for (int mi = 0; mi < 2; ++mi)
        av[mi][kk] = *(const f16x8*)(Aslot + (size_t)(wm * 128 + (mi + 2) * 32 + n31) * BK + coff);
    }
    if (t + 3 < nt) stageB(t + 3);
    {
      int ahead = nt - 1 - t;
      if (ahead >= 3)      asm volatile("s_waitcnt vmcnt(8)" ::: "memory");
      else if (ahead == 2) asm volatile("s_waitcnt vmcnt(4)" ::: "memory");
      else if (ahead == 1) asm volatile("s_waitcnt vmcnt(0)" ::: "memory");
    }
    BAR;
    __builtin_amdgcn_s_setprio(1);
#pragma unroll
    for (int kk = 0; kk < 2; ++kk)
#pragma unroll
      for (int mi = 0; mi < 2; ++mi)
#pragma unroll
        for (int ni = 0; ni < 2; ++ni)
          acc[mi + 2][ni] = __builtin_amdgcn_mfma_f32_32x32x16_f16(av[mi][kk], bv[ni][kk], acc[mi + 2][ni], 0, 0, 0);
    __builtin_amdgcn_s_setprio(0);
    BAR;
  }

#undef BAR
#undef FENCE

  const float* be = bias + (size_t)e * N;
#pragma unroll
  for (int mi = 0; mi < 4; ++mi) {
#pragma unroll
    for (int reg = 0; reg < 16; ++reg) {
      int row = m0 + wm * 128 + mi * 32 + 4 * khalf + (reg & 3) + 8 * (reg >> 2);
      size_t rowoff = ((size_t)e * CAP + row) * N;
#pragma unroll
      for (int ni = 0; ni < 2; ++ni) {
        int col = bx * BN + wn * 64 + ni * 32 + n31;
        float v = acc[mi][ni][reg] + be[col];
        if constexpr (GELU) v = fast_gelu(v);
        if constexpr (OUTF16) ((_Float16*)Cout)[rowoff + col] = (_Float16)v;
        else                  ((float*)Cout)[rowoff + col] = v;
      }
    }
  }
}

// ---------------- combine: out[t] = sum_k w_k * ybuf[slot_k] ----------------
__global__ __launch_bounds__(256) void combine_kernel(
    const float* __restrict__ ybuf, const int* __restrict__ assign_slot,
    const float* __restrict__ topk_w, float* __restrict__ out)
{
  int t = blockIdx.x;
  int s0 = assign_slot[t*2+0], s1 = assign_slot[t*2+1];
  float w0 = topk_w[t*2+0], w1 = topk_w[t*2+1];
  float4 a = {0.f, 0.f, 0.f, 0.f};
  int j = threadIdx.x;
  if (s0 >= 0) {
    float4 y = ((const float4*)(ybuf + (size_t)s0 * DM))[j];
    a.x += w0*y.x; a.y += w0*y.y; a.z += w0*y.z; a.w += w0*y.w;
  }
  if (s1 >= 0) {
    float4 y = ((const float4*)(ybuf + (size_t)s1 * DM))[j];
    a.x += w1*y.x; a.y += w1*y.y; a.z += w1*y.z; a.w += w1*y.w;
  }
  ((float4*)(out + (size_t)t * DM))[j] = a;
}

extern "C" void kernel_launch(void* const* d_in, const int* in_sizes, int n_in,
                              void* d_out, int out_size, void* d_ws, size_t ws_size,
                              hipStream_t stream)
{
  (void)in_sizes; (void)n_in; (void)out_size; (void)ws_size;
  const float* x  = (const float*)d_in[0];
  const float* Wr = (const float*)d_in[1];
  const float* br = (const float*)d_in[2];
  const float* W1 = (const float*)d_in[3];
  const float* b1 = (const float*)d_in[4];
  const float* W2 = (const float*)d_in[5];
  const float* b2 = (const float*)d_in[6];
  float* out = (float*)d_out;

  char* wsp = (char*)d_ws;
  size_t off = 0;
  auto take = [&](size_t bytes) { char* p = wsp + off; off += (bytes + 255) & ~(size_t)255; return p; };
  _Float16* W2t  = (_Float16*)take((size_t)NE * DM * FF * 2);   // [E][d][f]
  _Float16* W1t  = (_Float16*)take((size_t)NE * FF * DM * 2);   // [E][f][d]
  _Float16* xbuf = (_Float16*)take((size_t)NE * CAP * DM * 2);  // [E][cap][d]
  _Float16* hbuf = (_Float16*)take((size_t)NE * CAP * FF * 2);  // [E][cap][f]
  float*    ybuf = (float*)take((size_t)NE * CAP * DM * 4);     // [E][cap][d]
  int*   topk_e      = (int*)take((size_t)T_TOK * KTOP * 4);
  float* topk_w      = (float*)take((size_t)T_TOK * KTOP * 4);
  int*   assign_slot = (int*)take((size_t)T_TOK * KTOP * 4);
  int*   slot_token  = (int*)take((size_t)NE * CAP * 4);
  int*   counts      = (int*)take((size_t)NE * 4);
  int*   hist        = (int*)take((size_t)NCHUNK * NE * 4);
  int*   cbase       = (int*)take((size_t)NCHUNK * NE * 4);

  router_kernel<<<T_TOK / 4, 256, 0, stream>>>(x, Wr, br, topk_e, topk_w);
  hist_kernel<<<NCHUNK, 256, 0, stream>>>(topk_e, hist);
  prefix_kernel<<<1, 64, 0, stream>>>(hist, cbase, counts);
  assign_kernel<<<NCHUNK, 256, 0, stream>>>(topk_e, cbase, assign_slot, slot_token);
  transpose_f16<<<dim3(FF/64, DM/64, NE), 256, 0, stream>>>(W1, W1t, DM, FF);
  transpose_f16<<<dim3(DM/64, FF/64, NE), 256, 0, stream>>>(W2, W2t, FF, DM);
  gather_kernel<<<dim3(CAP, NE), 256, 0, stream>>>(x, slot_token, counts, xbuf);
  gemm8p<true,  true ><<<dim3(FF/256, CAP/256, NE), 512, 0, stream>>>(
      xbuf, W1t, b1, (void*)hbuf, counts, DM, FF);
  gemm8p<false, false><<<dim3(DM/256, CAP/256, NE), 512, 0, stream>>>(
      hbuf, W2t, b2, (void*)ybuf, counts, FF, DM);
  combine_kernel<<<T_TOK, 256, 0, stream>>>(ybuf, assign_slot, topk_w, out);
}

// Round 7
// 787.647 us; speedup vs baseline: 1.2009x; 1.2009x over previous
//
#include <hip/hip_runtime.h>
#include <cmath>

constexpr int T_TOK = 8192;   // B*S
constexpr int DM    = 1024;   // d
constexpr int FF    = 4096;   // f
constexpr int NE    = 8;      // experts
constexpr int KTOP  = 2;
constexpr int CAP   = 2560;   // ceil(1.25 * T*K / E)
constexpr int NCHUNK = (T_TOK * KTOP) / 256;   // 64 chunks for the FCFS scan

typedef _Float16 f16x8  __attribute__((ext_vector_type(8)));
typedef float    f32x16 __attribute__((ext_vector_type(16)));

__device__ __forceinline__ void glds16(const void* g, void* l) {
  __builtin_amdgcn_global_load_lds(
      (const __attribute__((address_space(1))) unsigned int*)g,
      (__attribute__((address_space(3))) unsigned int*)l, 16, 0, 0);
}

// sigmoid-form tanh-GELU (algebraically identical to the tanh form, fewer VALU)
__device__ __forceinline__ float fast_gelu(float v) {
  float t = __builtin_fmaf(v * v, -0.0713548162f, -1.5957691216f);
  float e = __expf(v * t);
  return v / (1.0f + e);
}

// ---------------- router: fp64 logits/softmax/top-2, one wave per token ----------------
__global__ __launch_bounds__(256) void router_kernel(
    const float* __restrict__ x, const float* __restrict__ Wr,
    const float* __restrict__ br, int* __restrict__ topk_e, float* __restrict__ topk_w)
{
  int wave = threadIdx.x >> 6, lane = threadIdx.x & 63;
  int t = blockIdx.x * 4 + wave;
  const float4* xr4 = (const float4*)(x + (size_t)t * DM);
  double acc[NE];
#pragma unroll
  for (int e = 0; e < NE; ++e) acc[e] = 0.0;
#pragma unroll
  for (int it = 0; it < DM / 4 / 64; ++it) {
    int j4 = it * 64 + lane;
    float4 xv = xr4[j4];
    const float* wr = Wr + (size_t)j4 * 4 * NE;
    float xs[4] = {xv.x, xv.y, xv.z, xv.w};
#pragma unroll
    for (int s = 0; s < 4; ++s) {
      double xd = (double)xs[s];
#pragma unroll
      for (int e = 0; e < NE; ++e) acc[e] += xd * (double)wr[s * NE + e];
    }
  }
#pragma unroll
  for (int off = 32; off >= 1; off >>= 1) {
#pragma unroll
    for (int e = 0; e < NE; ++e) acc[e] += __shfl_down(acc[e], off, 64);
  }
  if (lane == 0) {
    double mx = -1e300;
#pragma unroll
    for (int e = 0; e < NE; ++e) { acc[e] += (double)br[e]; if (acc[e] > mx) mx = acc[e]; }
    double p[NE]; double s = 0.0;
#pragma unroll
    for (int e = 0; e < NE; ++e) { p[e] = exp(acc[e] - mx); s += p[e]; }
#pragma unroll
    for (int e = 0; e < NE; ++e) p[e] /= s;
    int e1 = 0;
    for (int e = 1; e < NE; ++e) if (p[e] > p[e1]) e1 = e;           // ties -> lowest idx
    int e2 = (e1 == 0) ? 1 : 0;
    for (int e = 0; e < NE; ++e) { if (e == e1) continue; if (p[e] > p[e2]) e2 = e; }
    double wsum = p[e1] + p[e2]; if (wsum < 1e-9) wsum = 1e-9;
    topk_e[t*2+0] = e1; topk_e[t*2+1] = e2;
    topk_w[t*2+0] = (float)(p[e1] / wsum);
    topk_w[t*2+1] = (float)(p[e2] / wsum);
  }
}

// ---------------- FCFS capacity scan, parallel 3-phase ----------------
__global__ __launch_bounds__(256) void hist_kernel(
    const int* __restrict__ topk_e, int* __restrict__ hist)   // hist[NCHUNK][NE]
{
  __shared__ int wcnt[4][NE];
  int tid = threadIdx.x, lane = tid & 63, wave = tid >> 6;
  int e = topk_e[blockIdx.x * 256 + tid];
#pragma unroll
  for (int ee = 0; ee < NE; ++ee) {
    unsigned long long m = __ballot(e == ee);
    if (lane == 0) wcnt[wave][ee] = __popcll(m);
  }
  __syncthreads();
  if (tid < NE)
    hist[blockIdx.x * NE + tid] = wcnt[0][tid] + wcnt[1][tid] + wcnt[2][tid] + wcnt[3][tid];
}

__global__ __launch_bounds__(64) void prefix_kernel(
    const int* __restrict__ hist, int* __restrict__ base, int* __restrict__ counts)
{
  __shared__ int h[NCHUNK * NE];
  int t = threadIdx.x;
#pragma unroll
  for (int i = 0; i < (NCHUNK * NE) / 64; ++i) h[i * 64 + t] = hist[i * 64 + t];
  __syncthreads();
  if (t < NE) {
    int b = 0;
#pragma unroll
    for (int c = 0; c < NCHUNK; ++c) { base[c * NE + t] = b; b += h[c * NE + t]; }
    counts[t] = b < CAP ? b : CAP;
  }
}

__global__ __launch_bounds__(256) void assign_kernel(
    const int* __restrict__ topk_e, const int* __restrict__ base,
    int* __restrict__ assign_slot, int* __restrict__ slot_token)
{
  __shared__ int wcnt[4][NE];
  __shared__ int woff[4][NE];
  int tid = threadIdx.x, lane = tid & 63, wave = tid >> 6;
  int gi = blockIdx.x * 256 + tid;
  int e = topk_e[gi];
  int rank = 0;
  unsigned long long lt = (1ull << lane) - 1ull;
#pragma unroll
  for (int ee = 0; ee < NE; ++ee) {
    unsigned long long m = __ballot(e == ee);
    if (e == ee) rank = __popcll(m & lt);
    if (lane == 0) wcnt[wave][ee] = __popcll(m);
  }
  __syncthreads();
  if (tid < NE) {
    int b = base[blockIdx.x * NE + tid];
#pragma unroll
    for (int w = 0; w < 4; ++w) { woff[w][tid] = b; b += wcnt[w][tid]; }
  }
  __syncthreads();
  int pos = woff[wave][e] + rank;
  bool keep = pos < CAP;
  assign_slot[gi] = keep ? (e * CAP + pos) : -1;
  if (keep) slot_token[e * CAP + pos] = gi >> 1;   // K=2
}

// ---------------- merged W1+W2 transpose: fp32 [E][R][C] -> fp16 [E][C][R] ----------------
// One launch for both weights (saves a kernel dispatch). 64x64 tiles, 16B I/O.
__global__ __launch_bounds__(256) void transpose_all(
    const float* __restrict__ W1, _Float16* __restrict__ W1t,
    const float* __restrict__ W2, _Float16* __restrict__ W2t)
{
  __shared__ float tile[64][65];
  int b = blockIdx.x;
  const float* src; _Float16* dst; int R, C, r0, c0;
  if (b < 8192) {            // W1: R=DM rows, C=FF cols; tiles 64x x 16y per expert
    int e = b >> 10, t = b & 1023;
    R = DM; C = FF;
    src = W1 + (size_t)e * DM * FF; dst = W1t + (size_t)e * DM * FF;
    c0 = (t & 63) * 64; r0 = (t >> 6) * 64;
  } else {                   // W2: R=FF rows, C=DM cols; tiles 16x x 64y per expert
    int t2 = b - 8192; int e = t2 >> 10, t = t2 & 1023;
    R = FF; C = DM;
    src = W2 + (size_t)e * FF * DM; dst = W2t + (size_t)e * FF * DM;
    c0 = (t & 15) * 64; r0 = (t >> 4) * 64;
  }
  int t = threadIdx.x;
  int rr = t >> 4, cc = (t & 15) * 4;          // 16 in-rows per pass, float4 each
#pragma unroll
  for (int i = 0; i < 4; ++i) {
    float4 v = *(const float4*)(src + (size_t)(r0 + rr + i*16) * C + (c0 + cc));
    tile[rr + i*16][cc + 0] = v.x; tile[rr + i*16][cc + 1] = v.y;
    tile[rr + i*16][cc + 2] = v.z; tile[rr + i*16][cc + 3] = v.w;
  }
  __syncthreads();
  int oc = t >> 3, orr = (t & 7) * 8;          // 32 out-rows per pass, 8 fp16 each
#pragma unroll
  for (int i = 0; i < 2; ++i) {
    int c = oc + i * 32;
    _Float16 tmp[8];
#pragma unroll
    for (int j = 0; j < 8; ++j) tmp[j] = (_Float16)tile[orr + j][c];
    *(uint4*)(dst + (size_t)(c0 + c) * R + (r0 + orr)) = *(uint4*)tmp;
  }
}

// ---------------- gather kept tokens into [E][CAP][d] fp16 ----------------
__global__ __launch_bounds__(256) void gather_kernel(
    const float* __restrict__ x, const int* __restrict__ slot_token,
    const int* __restrict__ counts, _Float16* __restrict__ xbuf)
{
  int p = blockIdx.x, e = blockIdx.y;
  if (p >= counts[e]) return;
  int tkn = slot_token[e * CAP + p];
  float4 v = ((const float4*)(x + (size_t)tkn * DM))[threadIdx.x];
  _Float16 tmp[4] = {(_Float16)v.x, (_Float16)v.y, (_Float16)v.z, (_Float16)v.w};
  uint2 bits; __builtin_memcpy(&bits, tmp, 8);
  ((uint2*)(xbuf + ((size_t)e * CAP + p) * DM))[threadIdx.x] = bits;
}

// ---------------- fp16 MFMA GEMM: 128x64 per wave (R4xS2), BM=256 BN=128 BK=32 ----------------
// Change vs r5 (which measured 28% MfmaUtil, 0 bank conflicts): ONLY the wave->tile
// decomposition. r5's 64x64/wave issues 1.0 ds_read_b128 per MFMA ((2+2)/4) -> LDS-read
// bound at ~30% util (observed r0/r1/r5 invariant). 128x64/wave = (4+2)/8 = 0.75
// loads/MFMA (-25% LDS pressure) at acc=128 regs (still <=256 bucket -> 8 waves/CU,
// 2 blocks/CU at 24 KB LDS). Staging pattern, zero-conflict swizzle sw=(r^(r>>2))&3
// on 64-B rows (r5-verified: SQ_LDS_BANK_CONFLICT=0), 2-phase loop, and XCD remap
// are kept verbatim. Packing: GEMM2 = 8x8x8 = 512 eff blocks = 1.0 exact round
// (no split-K needed); GEMM1 = 32x8x8 = 2048 = 4.0 rounds.
template <bool GELU, bool OUTF16>
__global__ __launch_bounds__(256, 2) void gemm_rs(
    const _Float16* __restrict__ A, const _Float16* __restrict__ Bt,
    const float* __restrict__ bias, void* __restrict__ Cout,
    const int* __restrict__ counts, int K, int N)
{
  constexpr int BM = 256, BN = 128, BK = 32;
  __shared__ _Float16 As[BM * BK];   // [row][32 f16] = 64-B rows, 16 KB
  __shared__ _Float16 Bs[BN * BK];   // 8 KB

  // ---- XCD-aware bijective remap (grid products are multiples of 8) ----
  int nx = gridDim.x, ny = gridDim.y;
  int w = blockIdx.x + nx * (blockIdx.y + ny * blockIdx.z);
  int nwg = nx * ny * (int)gridDim.z;
  int q8 = nwg >> 3, r8 = nwg & 7;
  int xcd = w & 7, idx = w >> 3;
  int L = (xcd < r8 ? xcd * (q8 + 1) : r8 * (q8 + 1) + (xcd - r8) * q8) + idx;
  int bx = L % nx; int t1 = L / nx; int by = t1 % ny; int e = t1 / ny;

  int Me = counts[e];
  int m0 = by * BM;
  if (m0 >= Me) return;               // capacity padding: skip empty tiles (block-uniform)

  int tid = threadIdx.x, lane = tid & 63, wave = tid >> 6;
  int wm = wave >> 1, wn = wave & 1;  // 2Mx2N waves; wave owns 128(M) x 64(N)
  const _Float16* Ae = A + ((size_t)e * CAP + m0) * K;
  const _Float16* Be = Bt + ((size_t)e * N + (size_t)bx * BN) * K;
  int n31 = lane & 31, khalf = lane >> 5;
  int sw4 = (n31 ^ (n31 >> 2)) & 3;            // r5-verified zero-conflict read swizzle
  f32x16 acc[4][2] = {};

  for (int k0 = 0; k0 < K; k0 += BK) {
    // stage A (4 passes x 64 rows) and B (2 passes); dest = linear base + tid*16,
    // source chunk pre-swizzled with the same (row^(row>>2))&3 involution.
#pragma unroll
    for (int p = 0; p < 4; ++p) {
      int row = p * 64 + (tid >> 2);
      int csw = (tid & 3) ^ ((row ^ (row >> 2)) & 3);
      glds16(Ae + (size_t)row * K + (k0 + csw * 8), (char*)As + p * 4096 + tid * 16);
    }
#pragma unroll
    for (int p = 0; p < 2; ++p) {
      int row = p * 64 + (tid >> 2);
      int csw = (tid & 3) ^ ((row ^ (row >> 2)) & 3);
      glds16(Be + (size_t)row * K + (k0 + csw * 8), (char*)Bs + p * 4096 + tid * 16);
    }
    __syncthreads();
    const _Float16* Ab = As + (size_t)(wm * 128 + n31) * BK;
    const _Float16* Bb = Bs + (size_t)(wn * 64 + n31) * BK;
#pragma unroll
    for (int kk = 0; kk < 2; ++kk) {             // two 16-k steps
      int coff = (((kk * 2 + khalf) ^ sw4) << 3);
      f16x8 a0 = *(const f16x8*)(Ab + coff);
      f16x8 a1 = *(const f16x8*)(Ab + 1024 + coff);
      f16x8 a2 = *(const f16x8*)(Ab + 2048 + coff);
      f16x8 a3 = *(const f16x8*)(Ab + 3072 + coff);
      f16x8 b0 = *(const f16x8*)(Bb + coff);
      f16x8 b1 = *(const f16x8*)(Bb + 1024 + coff);
      acc[0][0] = __builtin_amdgcn_mfma_f32_32x32x16_f16(a0, b0, acc[0][0], 0, 0, 0);
      acc[0][1] = __builtin_amdgcn_mfma_f32_32x32x16_f16(a0, b1, acc[0][1], 0, 0, 0);
      acc[1][0] = __builtin_amdgcn_mfma_f32_32x32x16_f16(a1, b0, acc[1][0], 0, 0, 0);
      acc[1][1] = __builtin_amdgcn_mfma_f32_32x32x16_f16(a1, b1, acc[1][1], 0, 0, 0);
      acc[2][0] = __builtin_amdgcn_mfma_f32_32x32x16_f16(a2, b0, acc[2][0], 0, 0, 0);
      acc[2][1] = __builtin_amdgcn_mfma_f32_32x32x16_f16(a2, b1, acc[2][1], 0, 0, 0);
      acc[3][0] = __builtin_amdgcn_mfma_f32_32x32x16_f16(a3, b0, acc[3][0], 0, 0, 0);
      acc[3][1] = __builtin_amdgcn_mfma_f32_32x32x16_f16(a3, b1, acc[3][1], 0, 0, 0);
    }
    __syncthreads();
  }

  const float* be = bias + (size_t)e * N;
#pragma unroll
  for (int mi = 0; mi < 4; ++mi) {
#pragma unroll
    for (int reg = 0; reg < 16; ++reg) {
      int row = m0 + wm * 128 + mi * 32 + 4 * khalf + (reg & 3) + 8 * (reg >> 2);
      size_t rowoff = ((size_t)e * CAP + row) * N;
#pragma unroll
      for (int ni = 0; ni < 2; ++ni) {
        int col = bx * BN + wn * 64 + ni * 32 + n31;
        float v = acc[mi][ni][reg] + be[col];
        if constexpr (GELU) v = fast_gelu(v);
        if constexpr (OUTF16) ((_Float16*)Cout)[rowoff + col] = (_Float16)v;
        else                  ((float*)Cout)[rowoff + col] = v;
      }
    }
  }
}

// ---------------- combine: out[t] = sum_k w_k * ybuf[slot_k] ----------------
__global__ __launch_bounds__(256) void combine_kernel(
    const float* __restrict__ ybuf, const int* __restrict__ assign_slot,
    const float* __restrict__ topk_w, float* __restrict__ out)
{
  int t = blockIdx.x;
  int s0 = assign_slot[t*2+0], s1 = assign_slot[t*2+1];
  float w0 = topk_w[t*2+0], w1 = topk_w[t*2+1];
  float4 a = {0.f, 0.f, 0.f, 0.f};
  int j = threadIdx.x;
  if (s0 >= 0) {
    float4 y = ((const float4*)(ybuf + (size_t)s0 * DM))[j];
    a.x += w0*y.x; a.y += w0*y.y; a.z += w0*y.z; a.w += w0*y.w;
  }
  if (s1 >= 0) {
    float4 y = ((const float4*)(ybuf + (size_t)s1 * DM))[j];
    a.x += w1*y.x; a.y += w1*y.y; a.z += w1*y.z; a.w += w1*y.w;
  }
  ((float4*)(out + (size_t)t * DM))[j] = a;
}

extern "C" void kernel_launch(void* const* d_in, const int* in_sizes, int n_in,
                              void* d_out, int out_size, void* d_ws, size_t ws_size,
                              hipStream_t stream)
{
  (void)in_sizes; (void)n_in; (void)out_size; (void)ws_size;
  const float* x  = (const float*)d_in[0];
  const float* Wr = (const float*)d_in[1];
  const float* br = (const float*)d_in[2];
  const float* W1 = (const float*)d_in[3];
  const float* b1 = (const float*)d_in[4];
  const float* W2 = (const float*)d_in[5];
  const float* b2 = (const float*)d_in[6];
  float* out = (float*)d_out;

  char* wsp = (char*)d_ws;
  size_t off = 0;
  auto take = [&](size_t bytes) { char* p = wsp + off; off += (bytes + 255) & ~(size_t)255; return p; };
  _Float16* W2t  = (_Float16*)take((size_t)NE * DM * FF * 2);   // [E][d][f]
  _Float16* W1t  = (_Float16*)take((size_t)NE * FF * DM * 2);   // [E][f][d]
  _Float16* xbuf = (_Float16*)take((size_t)NE * CAP * DM * 2);  // [E][cap][d]
  _Float16* hbuf = (_Float16*)take((size_t)NE * CAP * FF * 2);  // [E][cap][f]
  float*    ybuf = (float*)take((size_t)NE * CAP * DM * 4);     // [E][cap][d]
  int*   topk_e      = (int*)take((size_t)T_TOK * KTOP * 4);
  float* topk_w      = (float*)take((size_t)T_TOK * KTOP * 4);
  int*   assign_slot = (int*)take((size_t)T_TOK * KTOP * 4);
  int*   slot_token  = (int*)take((size_t)NE * CAP * 4);
  int*   counts      = (int*)take((size_t)NE * 4);
  int*   hist        = (int*)take((size_t)NCHUNK * NE * 4);
  int*   cbase       = (int*)take((size_t)NCHUNK * NE * 4);

  router_kernel<<<T_TOK / 4, 256, 0, stream>>>(x, Wr, br, topk_e, topk_w);
  hist_kernel<<<NCHUNK, 256, 0, stream>>>(topk_e, hist);
  prefix_kernel<<<1, 64, 0, stream>>>(hist, cbase, counts);
  assign_kernel<<<NCHUNK, 256, 0, stream>>>(topk_e, cbase, assign_slot, slot_token);
  transpose_all<<<16384, 256, 0, stream>>>(W1, W1t, W2, W2t);
  gather_kernel<<<dim3(CAP, NE), 256, 0, stream>>>(x, slot_token, counts, xbuf);
  gemm_rs<true,  true ><<<dim3(FF/128, CAP/256, NE), 256, 0, stream>>>(
      xbuf, W1t, b1, (void*)hbuf, counts, DM, FF);
  gemm_rs<false, false><<<dim3(DM/128, CAP/256, NE), 256, 0, stream>>>(
      hbuf, W2t, b2, (void*)ybuf, counts, FF, DM);
  combine_kernel<<<T_TOK, 256, 0, stream>>>(ybuf, assign_slot, topk_w, out);
}